// Round 1
// baseline (166.225 us; speedup 1.0000x reference)
//
#include <hip/hip_runtime.h>

// StochaPolicy: out[b, 0:32] = phi_m @ w_m.T + b_m ; out[b,32:64] = exp(clip(phi_s @ w_s.T + b_s))
// phi_h[b,k] = exp(-(|x|^2 - 2 x.C_h[k] + |C_h[k]|^2) / (2|sigma_h[k]|))
// B=32768 D=256 K=1024 A=32. Fused bf16-MFMA kernel (phi ~ e^-40 ~ 0 -> bf16 safe).
//
// Block = 64 obs rows, 256 threads (4 waves). Loop 32 center-tiles of 64
// (tiles 0-15 = mean centers, 16-31 = std centers).
// GEMM1: wave w owns centers [16w,16w+16): mt=4 (all 64 rows) x nt=1, ks=8.
//        A-fragments (obs) preloaded to 128 VGPRs once -> only 8 ds_read_b128/wave/tile.
// phi:   C-layout (col=lane&15,row=(lane>>4)*4+reg) -> exp2 -> bf16 -> LDS (aliases cs).
// GEMM2: A-frags from phi LDS, B-frags (w) direct from L2-resident global.

typedef short bf16x8 __attribute__((ext_vector_type(8)));
typedef float floatx4 __attribute__((ext_vector_type(4)));
typedef unsigned short u16;

constexpr float LOG2E = 1.4426950408889634f;
constexpr int XLD = 264;   // bf16 elems per LDS row (256 + 8 pad: row stride = 4 banks -> 2-way, free)
constexpr int PLD = 72;    // phi LDS row stride (64 + 8)

__device__ __forceinline__ u16 f2bf(float f) {
  union { float f; unsigned u; } v; v.f = f;
  unsigned r = v.u + 0x7FFFu + ((v.u >> 16) & 1u);  // RNE
  return (u16)(r >> 16);
}
__device__ __forceinline__ float bf2f(u16 h) {
  union { unsigned u; float f; } v; v.u = ((unsigned)h) << 16;
  return v.f;
}

// ---------- prologue 1: centers -> bf16, c2[k]=|C_k|^2, s2[k]=log2e*0.5/|sigma_k| ----------
__global__ void prep_centers(const float* __restrict__ mC, const float* __restrict__ mS,
                             const float* __restrict__ sC, const float* __restrict__ sS,
                             u16* __restrict__ Cb, float* __restrict__ c2g,
                             float* __restrict__ s2g)
{
  const int b = blockIdx.x;            // 0..2047 combined center index
  const int half = b >> 10;
  const int k = b & 1023;
  const float* src = (half ? sC : mC) + (size_t)k * 256;
  const int t = threadIdx.x;           // 64 threads = 1 wave
  float4 f = *(const float4*)(src + t * 4);
  float ss = f.x*f.x + f.y*f.y + f.z*f.z + f.w*f.w;
  ushort4 o;
  o.x = f2bf(f.x); o.y = f2bf(f.y); o.z = f2bf(f.z); o.w = f2bf(f.w);
  *(ushort4*)(Cb + (size_t)b * 256 + t * 4) = o;
  for (int off = 32; off > 0; off >>= 1) ss += __shfl_down(ss, off, 64);
  if (t == 0) {
    c2g[b] = ss;
    float sig = (half ? sS : mS)[k];
    s2g[b] = LOG2E * 0.5f / fabsf(sig);
  }
}

// ---------- prologue 2: w -> bf16, layout wb[(half*32+a)*1024 + k] ----------
__global__ void prep_w(const float* __restrict__ mw, const float* __restrict__ sw,
                       u16* __restrict__ wb)
{
  int i = blockIdx.x * 256 + threadIdx.x;   // 0..65535
  int half = i >> 15;
  int rem = i & 32767;
  const float* src = half ? sw : mw;
  wb[i] = f2bf(src[rem]);
}

// ---------- main fused kernel ----------
__global__ __launch_bounds__(256, 2)
void policy_main(const float* __restrict__ obs,
                 const u16* __restrict__ Cb,
                 const float* __restrict__ c2g,
                 const float* __restrict__ s2g,
                 const u16* __restrict__ wb,
                 const float* __restrict__ mbias,
                 const float* __restrict__ sbias,
                 float* __restrict__ out)
{
  __shared__ u16 xs[64 * XLD];     // obs tile, bf16   (33792 B)
  __shared__ u16 cs[64 * XLD];     // center tile, bf16 (33792 B); aliased by phi after GEMM1
  __shared__ float c2t[64], s2t[64], x2s[64];

  const int tid  = threadIdx.x;
  const int lane = tid & 63;
  const int wv   = tid >> 6;       // wave 0..3
  const int lr   = lane & 15;
  const int lhi  = lane >> 4;      // 0..3
  const int row0 = blockIdx.x * 64;

  u16* phi_s = cs;                 // alias: phi[64][PLD] lives in cs after GEMM1 barrier

  // ---- stage obs tile fp32 -> bf16 LDS (coalesced: 32 lanes cover one row) ----
  {
    int r = tid >> 5;              // 0..7
    int c = (tid & 31) * 8;        // 0..248
    for (int i = 0; i < 8; ++i) {
      int row = i * 8 + r;
      const float* src = obs + (size_t)(row0 + row) * 256 + c;
      float4 f0 = *(const float4*)src;
      float4 f1 = *(const float4*)(src + 4);
      bf16x8 v;
      v[0] = (short)f2bf(f0.x); v[1] = (short)f2bf(f0.y);
      v[2] = (short)f2bf(f0.z); v[3] = (short)f2bf(f0.w);
      v[4] = (short)f2bf(f1.x); v[5] = (short)f2bf(f1.y);
      v[6] = (short)f2bf(f1.z); v[7] = (short)f2bf(f1.w);
      *(bf16x8*)(xs + row * XLD + c) = v;
    }
  }
  __syncthreads();

  // ---- x2[row] = sum_d x^2 (from bf16; phi ~ 0 so precision is moot) ----
  if (tid < 64) {
    float s = 0.f;
    for (int j = 0; j < 256; j += 8) {
      bf16x8 v = *(bf16x8*)(xs + tid * XLD + j);
      #pragma unroll
      for (int e = 0; e < 8; ++e) { float x = bf2f((u16)v[e]); s += x * x; }
    }
    x2s[tid] = s;
  }

  // ---- preload all A fragments (constant across the whole center loop) ----
  bf16x8 av[4][8];                 // 128 VGPRs
  #pragma unroll
  for (int m = 0; m < 4; ++m)
    #pragma unroll
    for (int ks = 0; ks < 8; ++ks)
      av[m][ks] = *(bf16x8*)(xs + (m * 16 + lr) * XLD + ks * 32 + lhi * 8);

  floatx4 acc2m[2], acc2s[2];
  #pragma unroll
  for (int n = 0; n < 2; ++n) {
    acc2m[n] = (floatx4){0.f, 0.f, 0.f, 0.f};
    acc2s[n] = (floatx4){0.f, 0.f, 0.f, 0.f};
  }

  for (int ct = 0; ct < 32; ++ct) {
    const int half = ct >> 4;
    __syncthreads();               // prev GEMM2 done reading phi (aliases cs)

    // stage center tile (bf16 global -> LDS) + per-center scalars
    {
      int r4  = tid >> 4;          // 0..15
      int c16 = (tid & 15) * 16;   // 0..240
      #pragma unroll
      for (int i = 0; i < 4; ++i) {
        int row = i * 16 + r4;
        const u16* src = Cb + (size_t)(ct * 64 + row) * 256 + c16;
        bf16x8 v0 = *(const bf16x8*)src;
        bf16x8 v1 = *(const bf16x8*)(src + 8);
        *(bf16x8*)(cs + row * XLD + c16) = v0;
        *(bf16x8*)(cs + row * XLD + c16 + 8) = v1;
      }
      if (tid < 64) { c2t[tid] = c2g[ct * 64 + tid]; s2t[tid] = s2g[ct * 64 + tid]; }
    }

    // GEMM2 B-fragments straight from global (L2-hot, 128 KB total) — issue early
    bf16x8 b2f[2][2];
    {
      const u16* wsrc = wb + (size_t)(half * 32) * 1024 + (ct & 15) * 64;
      #pragma unroll
      for (int ks2 = 0; ks2 < 2; ++ks2)
        #pragma unroll
        for (int nt2 = 0; nt2 < 2; ++nt2)
          b2f[ks2][nt2] = *(const bf16x8*)(wsrc + (nt2 * 16 + lr) * 1024 + ks2 * 32 + lhi * 8);
    }
    __syncthreads();

    // ---- GEMM1: wave's 16 centers x all 64 rows ----
    floatx4 acc1[4];
    #pragma unroll
    for (int m = 0; m < 4; ++m) acc1[m] = (floatx4){0.f, 0.f, 0.f, 0.f};
    #pragma unroll
    for (int ks = 0; ks < 8; ++ks) {
      bf16x8 bfr = *(bf16x8*)(cs + (wv * 16 + lr) * XLD + ks * 32 + lhi * 8);
      acc1[0] = __builtin_amdgcn_mfma_f32_16x16x32_bf16(av[0][ks], bfr, acc1[0], 0, 0, 0);
      acc1[1] = __builtin_amdgcn_mfma_f32_16x16x32_bf16(av[1][ks], bfr, acc1[1], 0, 0, 0);
      acc1[2] = __builtin_amdgcn_mfma_f32_16x16x32_bf16(av[2][ks], bfr, acc1[2], 0, 0, 0);
      acc1[3] = __builtin_amdgcn_mfma_f32_16x16x32_bf16(av[3][ks], bfr, acc1[3], 0, 0, 0);
    }
    __syncthreads();               // all waves done reading cs; safe to alias-write phi

    // ---- phi = exp2((2 dot - x2 - c2) * s2) -> bf16 -> LDS (C-layout -> A-layout round trip) ----
    {
      int colb = wv * 16 + lr;
      float c2v = c2t[colb];
      float s2v = s2t[colb];
      #pragma unroll
      for (int m = 0; m < 4; ++m)
        #pragma unroll
        for (int rg = 0; rg < 4; ++rg) {
          int rloc = m * 16 + lhi * 4 + rg;
          float ex = (2.f * acc1[m][rg] - x2s[rloc] - c2v) * s2v;
          phi_s[rloc * PLD + colb] = f2bf(exp2f(ex));
        }
    }
    __syncthreads();               // phi visible cross-wave

    // ---- GEMM2: out[16 rows][32] += phi[16][64] @ w.T[64][32] ----
    #pragma unroll
    for (int ks2 = 0; ks2 < 2; ++ks2) {
      bf16x8 a2 = *(bf16x8*)(phi_s + (wv * 16 + lr) * PLD + ks2 * 32 + lhi * 8);
      if (half == 0) {
        acc2m[0] = __builtin_amdgcn_mfma_f32_16x16x32_bf16(a2, b2f[ks2][0], acc2m[0], 0, 0, 0);
        acc2m[1] = __builtin_amdgcn_mfma_f32_16x16x32_bf16(a2, b2f[ks2][1], acc2m[1], 0, 0, 0);
      } else {
        acc2s[0] = __builtin_amdgcn_mfma_f32_16x16x32_bf16(a2, b2f[ks2][0], acc2s[0], 0, 0, 0);
        acc2s[1] = __builtin_amdgcn_mfma_f32_16x16x32_bf16(a2, b2f[ks2][1], acc2s[1], 0, 0, 0);
      }
    }
  }

  // ---- epilogue: bias, clip+exp for std, store ----
  #pragma unroll
  for (int nt2 = 0; nt2 < 2; ++nt2) {
    int col = nt2 * 16 + lr;
    float mb = mbias[col];
    float sb = sbias[col];
    #pragma unroll
    for (int rg = 0; rg < 4; ++rg) {
      int row = row0 + wv * 16 + lhi * 4 + rg;
      float m = acc2m[nt2][rg] + mb;
      float s = acc2s[nt2][rg] + sb;
      s = fminf(fmaxf(s, -20.f), 2.f);
      out[(size_t)row * 64 + col] = m;
      out[(size_t)row * 64 + 32 + col] = exp2f(s * LOG2E);
    }
  }
}

extern "C" void kernel_launch(void* const* d_in, const int* in_sizes, int n_in,
                              void* d_out, int out_size, void* d_ws, size_t ws_size,
                              hipStream_t stream) {
  const float* obs = (const float*)d_in[0];
  const float* mC  = (const float*)d_in[1];
  const float* mS  = (const float*)d_in[2];
  const float* mW  = (const float*)d_in[3];
  const float* mB  = (const float*)d_in[4];
  const float* sC  = (const float*)d_in[5];
  const float* sS  = (const float*)d_in[6];
  const float* sW  = (const float*)d_in[7];
  const float* sB  = (const float*)d_in[8];
  float* out = (float*)d_out;

  // workspace layout (≈1.2 MB): Cb[2048*256] bf16 | c2[2048] f32 | s2[2048] f32 | wb[2*32*1024] bf16
  u16*   Cb  = (u16*)d_ws;
  float* c2g = (float*)((char*)d_ws + 2048 * 256 * 2);
  float* s2g = c2g + 2048;
  u16*   wb  = (u16*)(s2g + 2048);

  prep_centers<<<2048, 64, 0, stream>>>(mC, mS, sC, sS, Cb, c2g, s2g);
  prep_w<<<256, 256, 0, stream>>>(mW, sW, wb);
  policy_main<<<512, 256, 0, stream>>>(obs, Cb, c2g, s2g, wb, mB, sB, out);
}